// Round 4
// baseline (42.628 us; speedup 1.0000x reference)
//
#include <hip/hip_runtime.h>
#include <math.h>

#define H_IN   136
#define W_IN   200
#define HWP    (H_IN * W_IN)       // 27200
#define OH     272
#define OW     400
#define CH     8
#define CIN    8
#define NPARAM 169
#define NEG_LOG2E (-1.4426950408889634f)
#define CHUNK_PX  1024
#define NCHUNK    27               // ceil(27200 / 1024)

// Param layout per instance (169 floats):
//  [0..79] w0[8][10] | [80..143] w1[8][8] | [144..151] w2[8]
//  [152..159] b0[8]  | [160..167] b1[8]   | [168] b2

// ---------------- Kernel A: per-instance MLP -> t-space logits ----------------
// Writes lg[inst][p] = -log2(e) * logit(inst, p)   (so B can use exp2 directly)
__global__ __launch_bounds__(256, 5) void logits_kernel(
    const float* __restrict__ mask_feats,   // (N, 8, H, W)
    const float* __restrict__ params,       // (n_inst, 169)
    const float* __restrict__ locations,    // (n_inst, 2)
    const int*   __restrict__ im_inds,      // (n_inst,)
    const int*   __restrict__ fpn_levels,   // (n_inst,)
    const float* __restrict__ soi_tab,      // (5,)
    float* __restrict__ lg)                 // (n_inst, 27200) workspace
{
    const int inst = blockIdx.y;            // uniform -> scalar weight loads
    const float* P = params + inst * NPARAM;
    const float loc_x   = locations[2 * inst];
    const float loc_y   = locations[2 * inst + 1];
    const float inv_soi = 1.0f / soi_tab[fpn_levels[inst]];
    const float* F  = mask_feats + (size_t)im_inds[inst] * (CIN * HWP);
    float*       Lo = lg + (size_t)inst * HWP;

    const int ubase = (blockIdx.x * CHUNK_PX) >> 1;   // unit = 2 adjacent px

    #pragma unroll
    for (int it = 0; it < 2; ++it) {
        int u = ubase + threadIdx.x + it * 256;
        if (u < HWP / 2) {
            int p = 2 * u;
            int r = p / W_IN;
            int c = p - r * W_IN;                     // even, c+1 same row

            const float* Fp = F + p;
            float2 f[CIN];
            #pragma unroll
            for (int ch = 0; ch < CIN; ++ch)
                f[ch] = *(const float2*)(Fp + ch * HWP);

            float rx0 = (loc_x - (float)(c * 8 + 4)) * inv_soi;
            float rx1 = rx0 - 8.0f * inv_soi;
            float ry  = (loc_y - (float)(r * 8 + 4)) * inv_soi;

            float h0[CH][2];
            #pragma unroll
            for (int o = 0; o < CH; ++o) {
                float b  = P[152 + o];
                float wx = P[o * 10 + 0];
                float wy = P[o * 10 + 1];
                float a0 = fmaf(wx, rx0, b);
                float a1 = fmaf(wx, rx1, b);
                a0 = fmaf(wy, ry, a0);
                a1 = fmaf(wy, ry, a1);
                #pragma unroll
                for (int i = 0; i < CIN; ++i) {
                    float w = P[o * 10 + 2 + i];
                    a0 = fmaf(w, f[i].x, a0);
                    a1 = fmaf(w, f[i].y, a1);
                }
                h0[o][0] = fmaxf(a0, 0.0f);
                h0[o][1] = fmaxf(a1, 0.0f);
            }

            float h1[CH][2];
            #pragma unroll
            for (int o = 0; o < CH; ++o) {
                float b  = P[160 + o];
                float a0 = b, a1 = b;
                #pragma unroll
                for (int i = 0; i < CH; ++i) {
                    float w = P[80 + o * CH + i];
                    a0 = fmaf(w, h0[i][0], a0);
                    a1 = fmaf(w, h0[i][1], a1);
                }
                h1[o][0] = fmaxf(a0, 0.0f);
                h1[o][1] = fmaxf(a1, 0.0f);
            }

            float b2 = NEG_LOG2E * P[168];
            float t0 = b2, t1 = b2;
            #pragma unroll
            for (int i = 0; i < CH; ++i) {
                float w = NEG_LOG2E * P[144 + i];
                t0 = fmaf(w, h1[i][0], t0);
                t1 = fmaf(w, h1[i][1], t1);
            }
            *(float2*)(Lo + p) = make_float2(t0, t1);
        }
    }
}

// ---------------- Kernel B: 2x aligned-bilinear upsample + sigmoid ----------------
// out[y,x] = sigmoid(logit_interp); source index: j = max(coord-1, 0), i0 = j>>1,
// frac = (j&1)*0.5, rows/cols clamped to H-1 / W-1 (verified vs JAX semantics R1-R3).
// One thread = 8 consecutive output px; exactly one unit per thread (grid 6800).
__global__ __launch_bounds__(256) void upsample_kernel(
    const float* __restrict__ lg,           // (n_inst, 27200) t-space
    float* __restrict__ out)                // (n_inst, 272, 400)
{
    int g = blockIdx.x * 256 + threadIdx.x;     // < 128 * 272 * 50 = 1,740,800
    int inst = g / (OH * (OW / 8));             // / 13600
    int q    = g - inst * (OH * (OW / 8));
    int y    = q / (OW / 8);
    int t    = q - y * (OW / 8);

    const float* L = lg + (size_t)inst * HWP;

    int   jy  = max(y - 1, 0);
    int   a0i = jy >> 1;
    float fy  = (jy & 1) ? 0.5f : 0.0f;
    int r0 = min(a0i,     H_IN - 1);
    int r1 = min(a0i + 1, H_IN - 1);

    int cm = 4 * t;                              // <= 196
    int cp = max(cm - 4, 0);
    float4 m0 = *(const float4*)(L + r0 * W_IN + cm);
    float4 m1 = *(const float4*)(L + r1 * W_IN + cm);
    float4 p0 = *(const float4*)(L + r0 * W_IN + cp);
    float4 p1 = *(const float4*)(L + r1 * W_IN + cp);

    // row lerp (t-space; lerp commutes with the -log2e scale)
    float B = fmaf(fy, m1.x - m0.x, m0.x);
    float C = fmaf(fy, m1.y - m0.y, m0.y);
    float D = fmaf(fy, m1.z - m0.z, m0.z);
    float E = fmaf(fy, m1.w - m0.w, m0.w);
    float A = (t == 0) ? B : fmaf(fy, p1.w - p0.w, p0.w);

    float4 r0v, r1v;
    r0v.x = __builtin_amdgcn_rcpf(1.0f + __builtin_amdgcn_exp2f(0.5f * (A + B)));
    r0v.y = __builtin_amdgcn_rcpf(1.0f + __builtin_amdgcn_exp2f(B));
    r0v.z = __builtin_amdgcn_rcpf(1.0f + __builtin_amdgcn_exp2f(0.5f * (B + C)));
    r0v.w = __builtin_amdgcn_rcpf(1.0f + __builtin_amdgcn_exp2f(C));
    r1v.x = __builtin_amdgcn_rcpf(1.0f + __builtin_amdgcn_exp2f(0.5f * (C + D)));
    r1v.y = __builtin_amdgcn_rcpf(1.0f + __builtin_amdgcn_exp2f(D));
    r1v.z = __builtin_amdgcn_rcpf(1.0f + __builtin_amdgcn_exp2f(0.5f * (D + E)));
    r1v.w = __builtin_amdgcn_rcpf(1.0f + __builtin_amdgcn_exp2f(E));

    float* Op = out + (size_t)inst * (OH * OW) + y * OW + 8 * t;
    *(float4*)(Op)     = r0v;
    *(float4*)(Op + 4) = r1v;
}

extern "C" void kernel_launch(void* const* d_in, const int* in_sizes, int n_in,
                              void* d_out, int out_size, void* d_ws, size_t ws_size,
                              hipStream_t stream) {
    const float* mask_feats = (const float*)d_in[0];
    const float* params     = (const float*)d_in[1];
    const float* locations  = (const float*)d_in[2];
    const int*   im_inds    = (const int*)d_in[3];
    const int*   fpn_levels = (const int*)d_in[4];
    const float* soi_tab    = (const float*)d_in[5];
    // d_in[6] = mask_feat_stride (== 8 here; factor-2 upsample baked in)

    const int n_inst = in_sizes[1] / NPARAM;   // 128
    float* lg = (float*)d_ws;                  // 128 * 27200 * 4 = 13.9 MB

    dim3 gA(NCHUNK, n_inst);
    logits_kernel<<<gA, 256, 0, stream>>>(
        mask_feats, params, locations, im_inds, fpn_levels, soi_tab, lg);

    const int total_units = n_inst * OH * (OW / 8);      // 1,740,800
    upsample_kernel<<<total_units / 256, 256, 0, stream>>>(lg, (float*)d_out);
}